// Round 19
// baseline (61.284 us; speedup 1.0000x reference)
//
#include <hip/hip_runtime.h>
#include <math.h>

#define N_PTS 16384
#define M_TGT 16384
#define TPN 8192
#define DUB2 4.0f
#define BMASK_WORDS (4*64*64*64/32)

__device__ __forceinline__ unsigned int mono_key(float f) {
    unsigned int u = __float_as_uint(f);
    return (u & 0x80000000u) ? ~u : (u | 0x80000000u);
}

// 33 integer offsets with dx^2+dy^2+dz^2 <= 4, grouped by d2 = 0,1,2,3,4.
__device__ const signed char NOFF[33][3] = {
    {0,0,0},
    {1,0,0},{-1,0,0},{0,1,0},{0,-1,0},{0,0,1},{0,0,-1},
    {1,1,0},{1,-1,0},{-1,1,0},{-1,-1,0},{1,0,1},{1,0,-1},{-1,0,1},{-1,0,-1},
    {0,1,1},{0,1,-1},{0,-1,1},{0,-1,-1},
    {1,1,1},{1,1,-1},{1,-1,1},{1,-1,-1},{-1,1,1},{-1,1,-1},{-1,-1,1},{-1,-1,-1},
    {2,0,0},{-2,0,0},{0,2,0},{0,-2,0},{0,0,2},{0,0,-2}
};

// K1: round-11 proven gemm (16 rows/block). Zeroes bmask.
__global__ __launch_bounds__(256) void k_gemm(const float* __restrict__ fea,
        const float* __restrict__ Wup, const float* __restrict__ Wcls,
        float* __restrict__ out_pred, float* __restrict__ out_fea,
        unsigned int* __restrict__ bmask) {
    __shared__ float Ws[64 * 64];
    __shared__ float fs[16 * 68];
    const int tid = threadIdx.x;
    const int r0 = blockIdx.x * 16;

    if (tid < 32) bmask[blockIdx.x * 32 + tid] = 0u;

    for (int t = tid; t < 1024; t += 256)
        ((float4*)Ws)[t] = ((const float4*)Wup)[t];
    {
        float4 v = ((const float4*)(fea + r0 * 64))[tid];
        int r = tid >> 4, c = (tid & 15) * 4;
        fs[r*68 + c + 0] = v.x; fs[r*68 + c + 1] = v.y;
        fs[r*68 + c + 2] = v.z; fs[r*68 + c + 3] = v.w;
    }
    __syncthreads();

    const int cg = tid & 15;
    const int r  = tid >> 4;
    float a0 = 0.f, a1 = 0.f, a2 = 0.f, a3 = 0.f;
    const float* fr = fs + r * 68;
    #pragma unroll
    for (int k = 0; k < 64; ++k) {
        float f = fr[k];
        float4 w = *(const float4*)&Ws[k * 64 + cg * 4];
        a0 = fmaf(f, w.x, a0); a1 = fmaf(f, w.y, a1);
        a2 = fmaf(f, w.z, a2); a3 = fmaf(f, w.w, a3);
    }
    a0 = fmaxf(a0, 0.f); a1 = fmaxf(a1, 0.f);
    a2 = fmaxf(a2, 0.f); a3 = fmaxf(a3, 0.f);
    const int row = r0 + r;
    *(float4*)&out_fea[row * 64 + cg * 4] = make_float4(a0, a1, a2, a3);

    float4 wc = *(const float4*)&Wcls[cg * 4];
    float s = a0*wc.x + a1*wc.y + a2*wc.z + a3*wc.w;
    for (int off = 1; off < 16; off <<= 1) s += __shfl_xor(s, off, 16);
    if (cg == 0) out_pred[row] = s;
}

// K2: 16 parallel blocks — bitmask build + per-block pass-0 partial histogram
// of mono_key(pred)>>24 (plain stores to phist, no init dependency).
__global__ __launch_bounds__(1024) void k_scat(const float* __restrict__ pred,
        const int* __restrict__ tc, unsigned int* __restrict__ bmask,
        unsigned int* __restrict__ phist) {
    __shared__ unsigned int whist[16][256];
    const int tid = threadIdx.x;
    const int blk = blockIdx.x;
    const int id = blk * 1024 + tid;

    for (int t = tid; t < 16 * 256; t += 1024) ((unsigned int*)whist)[t] = 0u;

    int4 c = *(const int4*)&tc[id * 4];
    int key = ((c.x * 64 + c.y) * 64 + c.z) * 64 + c.w;
    atomicOr(&bmask[key >> 5], 1u << (key & 31));

    __syncthreads();
    unsigned int u = mono_key(pred[id]);
    atomicAdd(&whist[tid >> 6][u >> 24], 1u);
    __syncthreads();
    if (tid < 256) {
        unsigned int s = 0u;
        #pragma unroll
        for (int w = 0; w < 16; ++w) s += whist[w][tid];
        phist[blk * 256 + tid] = s;
    }
}

// K3: redundant per-block select (sum phist -> 3 prefix-filtered scans of pred,
// identical math to the proven radix select -> identical thres in every block)
// + bitmask-probe NN + epilogue. 64 rows/block, 256 threads, 256 blocks.
__global__ __launch_bounds__(256) void k_final(const int* __restrict__ coords,
        const unsigned int* __restrict__ bmask, const unsigned int* __restrict__ phist,
        const float* __restrict__ out_pred, float* __restrict__ out_fea,
        float* __restrict__ out_keep, float* __restrict__ out_kt,
        float* __restrict__ out_loss) {
    __shared__ unsigned int lhist[256];
    __shared__ unsigned int scanb[256];
    __shared__ unsigned int sh_prefix, sh_rank;
    __shared__ float kscale[64];
    const int tid = threadIdx.x;
    const int r0 = blockIdx.x * 64;

    // ---- select (redundant per block) ----
    {
        unsigned int s = 0u;
        #pragma unroll
        for (int b = 0; b < 16; ++b) s += phist[b * 256 + tid];
        lhist[tid] = s;
    }
    if (tid == 0) { sh_prefix = 0u; sh_rank = TPN - 1; }
    __syncthreads();

    for (int pass = 0; pass < 4; ++pass) {
        const int shift = 24 - pass * 8;
        const unsigned int prefix = sh_prefix;
        const unsigned int rank = sh_rank;
        if (pass > 0) {
            lhist[tid] = 0u;
            __syncthreads();
            for (int i = tid; i < N_PTS; i += 256) {
                unsigned int u = mono_key(out_pred[i]);
                if ((u >> (shift + 8)) == prefix)
                    atomicAdd(&lhist[(u >> shift) & 255u], 1u);
            }
            __syncthreads();
        }
        if (tid < 64) {                      // single-wave inclusive scan (256 bins)
            uint4 h = ((const uint4*)lhist)[tid];
            unsigned int s0 = h.x, s1 = s0 + h.y, s2 = s1 + h.z, s3 = s2 + h.w;
            unsigned int tot = s3;
            for (int d = 1; d < 64; d <<= 1) {
                unsigned int v = __shfl_up(tot, d);
                if (tid >= d) tot += v;
            }
            unsigned int base = tot - s3;
            scanb[tid*4 + 0] = base + s0;
            scanb[tid*4 + 1] = base + s1;
            scanb[tid*4 + 2] = base + s2;
            scanb[tid*4 + 3] = base + s3;
        }
        __syncthreads();
        {
            unsigned int hi = scanb[tid];
            unsigned int lo = hi - lhist[tid];
            if (rank >= lo && rank < hi) {
                sh_prefix = (prefix << 8) | (unsigned int)tid;
                sh_rank = rank - lo;
            }
        }
        __syncthreads();
    }
    const unsigned int uth = sh_prefix;
    const float thres = (uth & 0x80000000u) ? __uint_as_float(uth ^ 0x80000000u)
                                            : __uint_as_float(~uth);

    // ---- probe + epilogue ----
    if (tid < 64) {
        const int i = r0 + tid;
        float p = out_pred[i];
        int4 c = *(const int4*)&coords[i * 4];
        const int b = c.x, x = c.y, y = c.z, z = c.w;
        int key0 = ((b * 64 + x) * 64 + y) * 64 + z;
        bool kt = (bmask[key0 >> 5] >> (key0 & 31)) & 1u;
        float dists;
        if (kt) {
            dists = 0.f;
        } else {
            dists = 5.f;                     // sentinel > DUB2: "not found"
            int t = 1;
            #pragma unroll
            for (int g = 1; g <= 4; ++g) {
                const int gend = (g == 1) ? 7 : (g == 2) ? 19 : (g == 3) ? 27 : 33;
                bool hit = false;
                for (; t < gend; ++t) {
                    int ox = x + NOFF[t][0], oy = y + NOFF[t][1], oz = z + NOFF[t][2];
                    if (((unsigned)ox | (unsigned)oy | (unsigned)oz) < 64u) {
                        int key = ((b * 64 + ox) * 64 + oy) * 64 + oz;
                        hit |= (bmask[key >> 5] >> (key & 31)) & 1u;
                    }
                }
                if (hit) { dists = (float)g; break; }
            }
        }
        bool keep0 = (p <= thres);
        bool pm = (p > DUB2), tm = (dists > DUB2);
        float loss = (pm && tm) ? p : ((!pm && tm) ? DUB2 : dists);
        bool kf = keep0 || kt;
        out_keep[i] = kf ? 1.f : 0.f;
        out_kt[i]  = kt ? 1.f : 0.f;
        out_loss[i] = loss;
        kscale[tid] = kf ? 1.f : 0.f;
    }
    __syncthreads();
    float4* fbase = (float4*)(out_fea + r0 * 64);
    #pragma unroll
    for (int q = 0; q < 4; ++q) {
        int v = tid + q * 256;               // 64 rows x 16 float4 = 1024
        float sc = kscale[v >> 4];
        float4 xv = fbase[v];
        xv.x *= sc; xv.y *= sc; xv.z *= sc; xv.w *= sc;
        fbase[v] = xv;
    }
}

extern "C" void kernel_launch(void* const* d_in, const int* in_sizes, int n_in,
                              void* d_out, int out_size, void* d_ws, size_t ws_size,
                              hipStream_t stream) {
    const float* fea     = (const float*)d_in[0];
    const float* Wup     = (const float*)d_in[1];
    const float* Wcls    = (const float*)d_in[2];
    const int*   coords  = (const int*)d_in[3];
    const int*   tcoords = (const int*)d_in[4];

    float* out      = (float*)d_out;
    float* out_pred = out;
    float* out_fea  = out + N_PTS;
    float* out_keep = out + N_PTS + N_PTS * 64;
    float* out_kt   = out_keep + N_PTS;
    float* out_loss = out_kt + N_PTS;

    char* ws = (char*)d_ws;
    unsigned int* bmask = (unsigned int*)(ws + 64);            // 128 KB -> 131136
    unsigned int* phist = (unsigned int*)(ws + 131136);        // 16 KB  (16 x 256 u32)

    k_gemm <<<N_PTS / 16, 256, 0, stream>>>(fea, Wup, Wcls, out_pred, out_fea, bmask);
    k_scat <<<M_TGT / 1024, 1024, 0, stream>>>(out_pred, tcoords, bmask, phist);
    k_final<<<N_PTS / 64, 256, 0, stream>>>(coords, bmask, phist,
                                            out_pred, out_fea, out_keep, out_kt, out_loss);
}

// Round 20
// 31.039 us; speedup vs baseline: 1.9744x; 1.9744x over previous
//
#include <hip/hip_runtime.h>
#include <math.h>

#define N_PTS 16384
#define M_TGT 16384
#define TPN 8192
#define DUB2 4.0f
#define BMASK_WORDS (4*64*64*64/32)

__device__ __forceinline__ unsigned int mono_key(float f) {
    unsigned int u = __float_as_uint(f);
    return (u & 0x80000000u) ? ~u : (u | 0x80000000u);
}

// 33 integer offsets with dx^2+dy^2+dz^2 <= 4, grouped by d2 = 0,1,2,3,4.
__device__ const signed char NOFF[33][3] = {
    {0,0,0},
    {1,0,0},{-1,0,0},{0,1,0},{0,-1,0},{0,0,1},{0,0,-1},
    {1,1,0},{1,-1,0},{-1,1,0},{-1,-1,0},{1,0,1},{1,0,-1},{-1,0,1},{-1,0,-1},
    {0,1,1},{0,1,-1},{0,-1,1},{0,-1,-1},
    {1,1,1},{1,1,-1},{1,-1,1},{1,-1,-1},{-1,1,1},{-1,1,-1},{-1,-1,1},{-1,-1,-1},
    {2,0,0},{-2,0,0},{0,2,0},{0,-2,0},{0,0,2},{0,0,-2}
};

// K1: round-11 proven gemm (16 rows/block). Zeroes bmask.
__global__ __launch_bounds__(256) void k_gemm(const float* __restrict__ fea,
        const float* __restrict__ Wup, const float* __restrict__ Wcls,
        float* __restrict__ out_pred, float* __restrict__ out_fea,
        unsigned int* __restrict__ bmask) {
    __shared__ float Ws[64 * 64];
    __shared__ float fs[16 * 68];
    const int tid = threadIdx.x;
    const int r0 = blockIdx.x * 16;

    if (tid < 32) bmask[blockIdx.x * 32 + tid] = 0u;

    for (int t = tid; t < 1024; t += 256)
        ((float4*)Ws)[t] = ((const float4*)Wup)[t];
    {
        float4 v = ((const float4*)(fea + r0 * 64))[tid];
        int r = tid >> 4, c = (tid & 15) * 4;
        fs[r*68 + c + 0] = v.x; fs[r*68 + c + 1] = v.y;
        fs[r*68 + c + 2] = v.z; fs[r*68 + c + 3] = v.w;
    }
    __syncthreads();

    const int cg = tid & 15;
    const int r  = tid >> 4;
    float a0 = 0.f, a1 = 0.f, a2 = 0.f, a3 = 0.f;
    const float* fr = fs + r * 68;
    #pragma unroll
    for (int k = 0; k < 64; ++k) {
        float f = fr[k];
        float4 w = *(const float4*)&Ws[k * 64 + cg * 4];
        a0 = fmaf(f, w.x, a0); a1 = fmaf(f, w.y, a1);
        a2 = fmaf(f, w.z, a2); a3 = fmaf(f, w.w, a3);
    }
    a0 = fmaxf(a0, 0.f); a1 = fmaxf(a1, 0.f);
    a2 = fmaxf(a2, 0.f); a3 = fmaxf(a3, 0.f);
    const int row = r0 + r;
    *(float4*)&out_fea[row * 64 + cg * 4] = make_float4(a0, a1, a2, a3);

    float4 wc = *(const float4*)&Wcls[cg * 4];
    float s = a0*wc.x + a1*wc.y + a2*wc.z + a3*wc.w;
    for (int off = 1; off < 16; off <<= 1) s += __shfl_xor(s, off, 16);
    if (cg == 0) out_pred[row] = s;
}

// K2: 16 parallel blocks — bitmask build + per-block pass-0 partial histogram
// of mono_key(pred)>>24 (plain stores to phist, no init dependency).
__global__ __launch_bounds__(1024) void k_scat(const float* __restrict__ pred,
        const int* __restrict__ tc, unsigned int* __restrict__ bmask,
        unsigned int* __restrict__ phist) {
    __shared__ unsigned int whist[16][256];
    const int tid = threadIdx.x;
    const int blk = blockIdx.x;
    const int id = blk * 1024 + tid;

    for (int t = tid; t < 16 * 256; t += 1024) ((unsigned int*)whist)[t] = 0u;

    int4 c = *(const int4*)&tc[id * 4];
    int key = ((c.x * 64 + c.y) * 64 + c.z) * 64 + c.w;
    atomicOr(&bmask[key >> 5], 1u << (key & 31));

    __syncthreads();
    unsigned int u = mono_key(pred[id]);
    atomicAdd(&whist[tid >> 6][u >> 24], 1u);
    __syncthreads();
    if (tid < 256) {
        unsigned int s = 0u;
        #pragma unroll
        for (int w = 0; w < 16; ++w) s += whist[w][tid];
        phist[blk * 256 + tid] = s;
    }
}

// K3: redundant per-block select with PROPER latency hiding: 1024 threads
// (16 waves/CU), float4 pred loads (4 vec-iters/pass vs 64 scalar), 16-way
// whist replication for pass>=1 (round-19's 4-wave scalar single-hist variant
// was latency-bound at 48 us). Identical math to proven round-11 select ->
// identical thres in every block. Then probe + epilogue, 64 rows/block.
__global__ __launch_bounds__(1024) void k_final(const int* __restrict__ coords,
        const unsigned int* __restrict__ bmask, const unsigned int* __restrict__ phist,
        const float* __restrict__ out_pred, float* __restrict__ out_fea,
        float* __restrict__ out_keep, float* __restrict__ out_kt,
        float* __restrict__ out_loss) {
    __shared__ unsigned int whist[16][256];     // 16 KB
    __shared__ unsigned int lhist[256];
    __shared__ unsigned int scanb[256];
    __shared__ unsigned int sh_prefix, sh_rank;
    __shared__ float kscale[64];
    const int tid = threadIdx.x;
    const int w = tid >> 6;
    const int r0 = blockIdx.x * 64;

    // ---- select (redundant per block) ----
    if (tid < 256) {
        unsigned int s = 0u;
        #pragma unroll
        for (int b = 0; b < 16; ++b) s += phist[b * 256 + tid];
        lhist[tid] = s;
    }
    if (tid == 0) { sh_prefix = 0u; sh_rank = TPN - 1; }
    __syncthreads();

    for (int pass = 0; pass < 4; ++pass) {
        const int shift = 24 - pass * 8;
        const unsigned int prefix = sh_prefix;
        const unsigned int rank = sh_rank;
        if (pass > 0) {
            for (int t = tid; t < 16 * 256; t += 1024) ((unsigned int*)whist)[t] = 0u;
            __syncthreads();
            for (int i = tid; i < N_PTS / 4; i += 1024) {
                float4 v = ((const float4*)out_pred)[i];
                unsigned int u0 = mono_key(v.x), u1 = mono_key(v.y);
                unsigned int u2 = mono_key(v.z), u3 = mono_key(v.w);
                if ((u0 >> (shift + 8)) == prefix) atomicAdd(&whist[w][(u0 >> shift) & 255u], 1u);
                if ((u1 >> (shift + 8)) == prefix) atomicAdd(&whist[w][(u1 >> shift) & 255u], 1u);
                if ((u2 >> (shift + 8)) == prefix) atomicAdd(&whist[w][(u2 >> shift) & 255u], 1u);
                if ((u3 >> (shift + 8)) == prefix) atomicAdd(&whist[w][(u3 >> shift) & 255u], 1u);
            }
            __syncthreads();
            if (tid < 256) {
                unsigned int s = 0u;
                #pragma unroll
                for (int ww = 0; ww < 16; ++ww) s += whist[ww][tid];
                lhist[tid] = s;
            }
            __syncthreads();
        }
        if (tid < 64) {                      // single-wave inclusive scan (256 bins)
            uint4 h = ((const uint4*)lhist)[tid];
            unsigned int s0 = h.x, s1 = s0 + h.y, s2 = s1 + h.z, s3 = s2 + h.w;
            unsigned int tot = s3;
            for (int d = 1; d < 64; d <<= 1) {
                unsigned int v = __shfl_up(tot, d);
                if (tid >= d) tot += v;
            }
            unsigned int base = tot - s3;
            scanb[tid*4 + 0] = base + s0;
            scanb[tid*4 + 1] = base + s1;
            scanb[tid*4 + 2] = base + s2;
            scanb[tid*4 + 3] = base + s3;
        }
        __syncthreads();
        if (tid < 256) {
            unsigned int hi = scanb[tid];
            unsigned int lo = hi - lhist[tid];
            if (rank >= lo && rank < hi) {
                sh_prefix = (prefix << 8) | (unsigned int)tid;
                sh_rank = rank - lo;
            }
        }
        __syncthreads();
    }
    const unsigned int uth = sh_prefix;
    const float thres = (uth & 0x80000000u) ? __uint_as_float(uth ^ 0x80000000u)
                                            : __uint_as_float(~uth);

    // ---- probe + epilogue ----
    if (tid < 64) {
        const int i = r0 + tid;
        float p = out_pred[i];
        int4 c = *(const int4*)&coords[i * 4];
        const int b = c.x, x = c.y, y = c.z, z = c.w;
        int key0 = ((b * 64 + x) * 64 + y) * 64 + z;
        bool kt = (bmask[key0 >> 5] >> (key0 & 31)) & 1u;
        float dists;
        if (kt) {
            dists = 0.f;
        } else {
            dists = 5.f;                     // sentinel > DUB2: "not found"
            int t = 1;
            #pragma unroll
            for (int g = 1; g <= 4; ++g) {
                const int gend = (g == 1) ? 7 : (g == 2) ? 19 : (g == 3) ? 27 : 33;
                bool hit = false;
                for (; t < gend; ++t) {
                    int ox = x + NOFF[t][0], oy = y + NOFF[t][1], oz = z + NOFF[t][2];
                    if (((unsigned)ox | (unsigned)oy | (unsigned)oz) < 64u) {
                        int key = ((b * 64 + ox) * 64 + oy) * 64 + oz;
                        hit |= (bmask[key >> 5] >> (key & 31)) & 1u;
                    }
                }
                if (hit) { dists = (float)g; break; }
            }
        }
        bool keep0 = (p <= thres);
        bool pm = (p > DUB2), tm = (dists > DUB2);
        float loss = (pm && tm) ? p : ((!pm && tm) ? DUB2 : dists);
        bool kf = keep0 || kt;
        out_keep[i] = kf ? 1.f : 0.f;
        out_kt[i]  = kt ? 1.f : 0.f;
        out_loss[i] = loss;
        kscale[tid] = kf ? 1.f : 0.f;
    }
    __syncthreads();
    {
        float4* fbase = (float4*)(out_fea + r0 * 64);
        int v = tid;                          // 64 rows x 16 float4 = 1024
        float sc = kscale[v >> 4];
        float4 xv = fbase[v];
        xv.x *= sc; xv.y *= sc; xv.z *= sc; xv.w *= sc;
        fbase[v] = xv;
    }
}

extern "C" void kernel_launch(void* const* d_in, const int* in_sizes, int n_in,
                              void* d_out, int out_size, void* d_ws, size_t ws_size,
                              hipStream_t stream) {
    const float* fea     = (const float*)d_in[0];
    const float* Wup     = (const float*)d_in[1];
    const float* Wcls    = (const float*)d_in[2];
    const int*   coords  = (const int*)d_in[3];
    const int*   tcoords = (const int*)d_in[4];

    float* out      = (float*)d_out;
    float* out_pred = out;
    float* out_fea  = out + N_PTS;
    float* out_keep = out + N_PTS + N_PTS * 64;
    float* out_kt   = out_keep + N_PTS;
    float* out_loss = out_kt + N_PTS;

    char* ws = (char*)d_ws;
    unsigned int* bmask = (unsigned int*)(ws + 64);            // 128 KB -> 131136
    unsigned int* phist = (unsigned int*)(ws + 131136);        // 16 KB  (16 x 256 u32)

    k_gemm <<<N_PTS / 16, 256, 0, stream>>>(fea, Wup, Wcls, out_pred, out_fea, bmask);
    k_scat <<<M_TGT / 1024, 1024, 0, stream>>>(out_pred, tcoords, bmask, phist);
    k_final<<<N_PTS / 64, 1024, 0, stream>>>(coords, bmask, phist,
                                             out_pred, out_fea, out_keep, out_kt, out_loss);
}